// Round 1
// baseline (99.474 us; speedup 1.0000x reference)
//
#include <hip/hip_runtime.h>
#include <math.h>

#define N 1024
#define IN_DIM 16
#define HID 64
#define MAXD 64

__device__ __forceinline__ float sigmoidf_(float x) {
    return 1.0f / (1.0f + __expf(-x));
}

// ---------------- encoder: h[u][j] = tanh(X[u]·W_enc[j] + b_enc[j]) -------------
__global__ void encoder_kernel(const float* __restrict__ X,
                               const float* __restrict__ W_enc,
                               const float* __restrict__ b_enc,
                               float* __restrict__ h) {
    int idx = blockIdx.x * blockDim.x + threadIdx.x;
    if (idx >= N * HID) return;
    int u = idx >> 6;       // /HID
    int j = idx & (HID - 1);
    float acc = b_enc[j];
#pragma unroll
    for (int k = 0; k < IN_DIM; ++k)
        acc += X[u * IN_DIM + k] * W_enc[j * IN_DIM + k];
    h[idx] = tanhf(acc);
}

// ---------------- CSR build: one wave per row, ballot compaction ----------------
__global__ void build_csr_kernel(const float* __restrict__ A,
                                 const float* __restrict__ E,
                                 int* __restrict__ nbr,
                                 float* __restrict__ ev,
                                 float* __restrict__ deg) {
    int u = blockIdx.x;          // N blocks
    int lane = threadIdx.x;      // 64 threads = 1 wave
    int count = 0;
    for (int base = 0; base < N; base += 64) {
        int v = base + lane;
        float a = A[u * N + v];
        bool has = (a > 0.0f);
        unsigned long long ball = __ballot(has);
        int pre = __popcll(ball & ((1ull << lane) - 1ull));
        if (has) {
            int slot = count + pre;
            if (slot < MAXD) {
                nbr[u * MAXD + slot] = v;
                ev[u * MAXD + slot] = E[u * N + v];
            }
        }
        count += __popcll(ball);
    }
    if (lane == 0) deg[u] = (float)count;
}

// ---------------- proj: proj[v][j] = h[v]·Wm_h[j] + b_msg[j] --------------------
// W_msg is (HID, HID+1) row-major; Wm_h[j][k] = W_msg[j*(HID+1)+k]
__global__ void proj_kernel(const float* __restrict__ h,
                            const float* __restrict__ W_msg,
                            const float* __restrict__ b_msg,
                            float* __restrict__ proj) {
    int idx = blockIdx.x * blockDim.x + threadIdx.x;
    if (idx >= N * HID) return;
    int v = idx >> 6;
    int j = idx & (HID - 1);
    float acc = b_msg[j];
#pragma unroll
    for (int k = 0; k < HID; ++k)
        acc += h[v * HID + k] * W_msg[j * (HID + 1) + k];
    proj[idx] = acc;
}

// ---------------- fused message-aggregate + GRU, one wave per row u -------------
__global__ void step_kernel(const float* __restrict__ proj,
                            const float* __restrict__ W_msg,   // for w_e = col HID
                            const float* __restrict__ hin,
                            const int* __restrict__ nbr,
                            const float* __restrict__ ev,
                            const float* __restrict__ deg,
                            const float* __restrict__ W_ih,
                            const float* __restrict__ W_hh,
                            const float* __restrict__ b_ih,
                            const float* __restrict__ b_hh,
                            float* __restrict__ hout) {
    int wave = threadIdx.x >> 6;     // 4 waves / block
    int lane = threadIdx.x & 63;     // lane == hidden index j
    int u = blockIdx.x * 4 + wave;
    if (u >= N) return;

    __shared__ float sm[4][2][HID];  // per-wave: [0]=msgs, [1]=h_u

    float we = W_msg[lane * (HID + 1) + HID];  // w_e[lane]
    float d = deg[u];
    int dn = (int)d;
    float s = 0.0f;
    for (int i = 0; i < dn; ++i) {
        int v = nbr[u * MAXD + i];
        float e = ev[u * MAXD + i];
        s += tanhf(proj[v * HID + lane] + e * we);
    }
    float msg = (dn > 0) ? (s / d) : 0.0f;
    float hu = hin[u * HID + lane];

    sm[wave][0][lane] = msg;
    sm[wave][1][lane] = hu;
    __syncthreads();

    // lane j computes gate rows j (r), 64+j (z), 128+j (n)
    float gi[3], gh[3];
#pragma unroll
    for (int g = 0; g < 3; ++g) {
        int row = g * HID + lane;
        float accI = b_ih[row];
        float accH = b_hh[row];
#pragma unroll 8
        for (int k = 0; k < HID; ++k) {
            float mk = sm[wave][0][k];
            float hk = sm[wave][1][k];
            accI += mk * W_ih[row * HID + k];
            accH += hk * W_hh[row * HID + k];
        }
        gi[g] = accI;
        gh[g] = accH;
    }
    float r = sigmoidf_(gi[0] + gh[0]);
    float z = sigmoidf_(gi[1] + gh[1]);
    float n = tanhf(gi[2] + r * gh[2]);
    hout[u * HID + lane] = (1.0f - z) * n + z * hu;
}

// ---------------- readout: scalar sigmoid(MLP(cat(h[s], h[t]))) ------------------
__global__ void readout_kernel(const float* __restrict__ h,
                               const float* __restrict__ W_r1,
                               const float* __restrict__ b_r1,
                               const float* __restrict__ W_r2,
                               const float* __restrict__ b_r2,
                               const int* __restrict__ src,
                               const int* __restrict__ tgt,
                               float* __restrict__ out) {
    int lane = threadIdx.x;  // 64 threads, 1 wave; lane = hidden row of W_r1
    int sI = src[0];
    int tI = tgt[0];
    float acc = b_r1[lane];
#pragma unroll 8
    for (int k = 0; k < HID; ++k)
        acc += h[sI * HID + k] * W_r1[lane * (2 * HID) + k];
#pragma unroll 8
    for (int k = 0; k < HID; ++k)
        acc += h[tI * HID + k] * W_r1[lane * (2 * HID) + HID + k];
    float hid = fmaxf(acc, 0.0f);
    float p = hid * W_r2[lane];
#pragma unroll
    for (int off = 32; off > 0; off >>= 1)
        p += __shfl_down(p, off);
    if (lane == 0) out[0] = sigmoidf_(p + b_r2[0]);
}

extern "C" void kernel_launch(void* const* d_in, const int* in_sizes, int n_in,
                              void* d_out, int out_size, void* d_ws, size_t ws_size,
                              hipStream_t stream) {
    const float* A     = (const float*)d_in[0];
    const float* E     = (const float*)d_in[1];
    const float* X     = (const float*)d_in[2];
    const float* W_enc = (const float*)d_in[3];
    const float* b_enc = (const float*)d_in[4];
    const float* W_msg = (const float*)d_in[5];
    const float* b_msg = (const float*)d_in[6];
    const float* W_ih  = (const float*)d_in[7];
    const float* W_hh  = (const float*)d_in[8];
    const float* b_ih  = (const float*)d_in[9];
    const float* b_hh  = (const float*)d_in[10];
    const float* W_r1  = (const float*)d_in[11];
    const float* b_r1  = (const float*)d_in[12];
    const float* W_r2  = (const float*)d_in[13];
    const float* b_r2  = (const float*)d_in[14];
    const int*   src   = (const int*)d_in[15];
    const int*   tgt   = (const int*)d_in[16];
    // steps is fixed at 3 in the reference problem; hardcoded below.

    // workspace layout (floats)
    float* ws   = (float*)d_ws;
    float* h0   = ws;                    // N*HID
    float* h1   = h0 + N * HID;          // N*HID
    float* proj = h1 + N * HID;          // N*HID
    float* deg  = proj + N * HID;        // N
    float* ev   = deg + N;               // N*MAXD
    int*   nbr  = (int*)(ev + N * MAXD); // N*MAXD ints

    encoder_kernel<<<(N * HID) / 256, 256, 0, stream>>>(X, W_enc, b_enc, h0);
    build_csr_kernel<<<N, 64, 0, stream>>>(A, E, nbr, ev, deg);

    float* hc = h0;
    float* hn = h1;
    for (int s = 0; s < 3; ++s) {
        proj_kernel<<<(N * HID) / 256, 256, 0, stream>>>(hc, W_msg, b_msg, proj);
        step_kernel<<<N / 4, 256, 0, stream>>>(proj, W_msg, hc, nbr, ev, deg,
                                               W_ih, W_hh, b_ih, b_hh, hn);
        float* t = hc; hc = hn; hn = t;
    }

    readout_kernel<<<1, 64, 0, stream>>>(hc, W_r1, b_r1, W_r2, b_r2, src, tgt,
                                         (float*)d_out);
}